// Round 18
// baseline (181.272 us; speedup 1.0000x reference)
//
#include <hip/hip_runtime.h>
#include <math.h>

// ---------------------------------------------------------------------------
// MyNet: two 1024x1024x3 images -> 3x3 matrix.
// R18: R15-exact structure; ONE algorithmic change: pixel-match SSD computed
//      as ||n||^2 + ||y||^2 - 2 n.y. Per-pixel norms produced in coding
//      (channels already in regs, 32 fma) into cn (512^2, aliased onto feat
//      ch40-47) and pn (256^2). pm512/pm256 taps: 8 fma dot vs 8 sub + 8 fma
//      -> SSD core VALU halved (mid is VALU-count-bound at 67% busy).
// ---------------------------------------------------------------------------

__global__ void fuse_weights_kernel(const float* __restrict__ enc_w,
                                    const float* __restrict__ enc_b,
                                    const float* __restrict__ embed_w,
                                    const float* __restrict__ embed_b,
                                    float* __restrict__ weff_t,
                                    float* __restrict__ beff) {
    int t = threadIdx.x;
    for (int idx = t; idx < 27 * 32; idx += blockDim.x) {
        int r = idx >> 5, o = idx & 31;
        float s = 0.f;
        for (int k = 0; k < 24; ++k) s += embed_w[o * 24 + k] * enc_w[k * 27 + r];
        weff_t[idx] = s;
    }
    if (t < 32) {
        float s = embed_b[t];
        for (int k = 0; k < 24; ++k) s += embed_w[t * 24 + k] * enc_b[k];
        beff[t] = s;
    }
}

// Fused enc+embed 3x3 conv (3->32) + maxpool2 -> c (512^2, ch-last) + norms
// cn, + maxpool2 -> p (256^2, ch-last) + norms pn. Weights wave-uniform.
__global__ __launch_bounds__(256) void coding_kernel(
    const float* __restrict__ x1, const float* __restrict__ x2,
    const float* __restrict__ weff_t, const float* __restrict__ beff,
    float* __restrict__ c1, float* __restrict__ c2,
    float* __restrict__ p1, float* __restrict__ p2,
    float* __restrict__ cn1, float* __restrict__ cn2,
    float* __restrict__ pn1, float* __restrict__ pn2) {
    int tx = threadIdx.x, ty = threadIdx.y;
    int img = blockIdx.z;
    const float* x = img ? x2 : x1;
    float* c = img ? c2 : c1;
    float* p = img ? p2 : p1;
    float* cn = img ? cn2 : cn1;
    float* pn = img ? pn2 : pn1;
    int Y = blockIdx.y * 16 + ty;   // src row 0..1023
    int cx = blockIdx.x * 16 + tx;  // c col 0..511
    int X0 = 2 * cx;
    bool interior = (blockIdx.y > 0 && blockIdx.y < 63 &&
                     blockIdx.x > 0 && blockIdx.x < 31);
    float acc0[32], acc1[32];
#pragma unroll
    for (int o = 0; o < 32; ++o) {
        acc0[o] = beff[o];
        acc1[o] = acc0[o];
    }
#pragma unroll 1
    for (int ci = 0; ci < 3; ++ci) {
        float in[3][4];
        const float* xc = x + ci * 1048576;
        if (interior) {
#pragma unroll
            for (int r = 0; r < 3; ++r) {
                const float* row = xc + (Y - 1 + r) * 1024 + X0 - 1;
#pragma unroll
                for (int q = 0; q < 4; ++q) in[r][q] = row[q];
            }
        } else {
#pragma unroll
            for (int r = 0; r < 3; ++r)
#pragma unroll
                for (int q = 0; q < 4; ++q) {
                    int gy = Y - 1 + r, gx = X0 - 1 + q;
                    in[r][q] = (gy >= 0 && gy < 1024 && gx >= 0 && gx < 1024)
                                   ? xc[gy * 1024 + gx]
                                   : 0.f;
                }
        }
#pragma unroll
        for (int ky = 0; ky < 3; ++ky)
#pragma unroll
            for (int kx = 0; kx < 3; ++kx) {
                const float* wrow = weff_t + (ci * 9 + ky * 3 + kx) * 32;
                float xa = in[ky][kx];
                float xb = in[ky][kx + 1];
#pragma unroll
                for (int o = 0; o < 32; ++o) {
                    float wv = wrow[o];  // wave-uniform -> SGPR
                    acc0[o] = fmaf(wv, xa, acc0[o]);
                    acc1[o] = fmaf(wv, xb, acc1[o]);
                }
            }
    }
#pragma unroll
    for (int o = 0; o < 32; ++o) {
        float m = fmaxf(acc0[o], acc1[o]);
        acc0[o] = fmaxf(m, __shfl_xor(m, 16, 64));
    }
    float cnorm = 0.f;
#pragma unroll
    for (int o = 0; o < 32; ++o) cnorm = fmaf(acc0[o], acc0[o], cnorm);
    int cpix = (Y >> 1) * 512 + cx;
    if ((ty & 1) == 0) {
        float4* cd = (float4*)(c + cpix * 32);
#pragma unroll
        for (int q = 0; q < 8; ++q)
            cd[q] = make_float4(acc0[4 * q], acc0[4 * q + 1], acc0[4 * q + 2],
                                acc0[4 * q + 3]);
        cn[cpix] = cnorm;
    }
#pragma unroll
    for (int o = 0; o < 32; ++o) {
        float v = fmaxf(acc0[o], __shfl_xor(acc0[o], 1, 64));
        acc0[o] = fmaxf(v, __shfl_xor(v, 32, 64));
    }
    float pnorm = 0.f;
#pragma unroll
    for (int o = 0; o < 32; ++o) pnorm = fmaf(acc0[o], acc0[o], pnorm);
    if (((ty & 3) == 0) && ((tx & 1) == 0)) {
        int ppix = (Y >> 2) * 256 + (cx >> 1);
        float4* pd = (float4*)(p + ppix * 32);
#pragma unroll
        for (int q = 0; q < 8; ++q)
            pd[q] = make_float4(acc0[4 * q], acc0[4 * q + 1], acc0[4 * q + 2],
                                acc0[4 * q + 3]);
        pn[ppix] = pnorm;
    }
}

// Fused middle stage: [0,4096) pm512; [4096,5120) pm256; [5120,5632)
// dense_part. pm branches use norm/dot SSD. Dense branch R15-exact.
__global__ __launch_bounds__(256) void mid_kernel(
    const float* __restrict__ c1, const float* __restrict__ c2,
    const float* __restrict__ p1, const float* __restrict__ p2,
    const float* __restrict__ cn1, const float* __restrict__ cn2,
    const float* __restrict__ pn1, const float* __restrict__ pn2,
    const float* __restrict__ dw, float* __restrict__ feat,
    float* __restrict__ part) {
    __shared__ float smem[4 * 1296 + 4 * 8 * 28];  // dense branch only
    int bid = blockIdx.x;
    int tid = threadIdx.x;
    if (bid < 4096) {
        // -------- pm512 + pool -> feat ch0..19 (norm/dot SSD) --------
        int bx = bid & 63, by = bid >> 6;
        int quad = tid & 3;
        int pl = tid >> 2;
        int px = pl & 7, py = pl >> 3;
        int sw = bx * 8 + px;
        int sh = by * 8 + py;
        bool interior = (sh >= 1 && sh <= 510 && sw >= 1 && sw <= 510);
        const float* b1 = c1 + (sh * 512 + sw) * 32 + quad * 8;
        const float* b2 = c2 + (sh * 512 + sw) * 32 + quad * 8;
        float a1[9], a2[9];
#pragma unroll
        for (int k = 0; k < 9; ++k) { a1[k] = 0.f; a2[k] = 0.f; }
        if (interior) {
            float4 y1a = ((const float4*)b1)[0], y1b = ((const float4*)b1)[1];
            float4 y2a = ((const float4*)b2)[0], y2b = ((const float4*)b2)[1];
#pragma unroll
            for (int dh = -1; dh <= 1; ++dh)
#pragma unroll
                for (int dwp = -1; dwp <= 1; ++dwp) {
                    int k = (dh + 1) * 3 + (dwp + 1);
                    const float4* n1 =
                        (const float4*)(b1 + (dh * 512 + dwp) * 32);
                    const float4* n2 =
                        (const float4*)(b2 + (dh * 512 + dwp) * 32);
                    float4 na = n1[0], nA = n1[1], nb = n2[0], nB = n2[1];
                    float d1 = 0.f, d2 = 0.f;
                    d1 = fmaf(na.x, y2a.x, d1);
                    d1 = fmaf(na.y, y2a.y, d1);
                    d1 = fmaf(na.z, y2a.z, d1);
                    d1 = fmaf(na.w, y2a.w, d1);
                    d1 = fmaf(nA.x, y2b.x, d1);
                    d1 = fmaf(nA.y, y2b.y, d1);
                    d1 = fmaf(nA.z, y2b.z, d1);
                    d1 = fmaf(nA.w, y2b.w, d1);
                    d2 = fmaf(nb.x, y1a.x, d2);
                    d2 = fmaf(nb.y, y1a.y, d2);
                    d2 = fmaf(nb.z, y1a.z, d2);
                    d2 = fmaf(nb.w, y1a.w, d2);
                    d2 = fmaf(nB.x, y1b.x, d2);
                    d2 = fmaf(nB.y, y1b.y, d2);
                    d2 = fmaf(nB.z, y1b.z, d2);
                    d2 = fmaf(nB.w, y1b.w, d2);
                    a1[k] = d1;
                    a2[k] = d2;
                }
        }
#pragma unroll
        for (int k = 0; k < 9; ++k) {
            a1[k] += __shfl_xor(a1[k], 1, 64);
            a1[k] += __shfl_xor(a1[k], 2, 64);
            a2[k] += __shfl_xor(a2[k], 1, 64);
            a2[k] += __shfl_xor(a2[k], 2, 64);
        }
        float d[20];
        if (interior) {
            float cn1c = cn1[sh * 512 + sw];
            float cn2c = cn2[sh * 512 + sw];
            float s1 = 0.f, s2 = 0.f;
#pragma unroll
            for (int dh = -1; dh <= 1; ++dh)
#pragma unroll
                for (int dwp = -1; dwp <= 1; ++dwp) {
                    int k = (dh + 1) * 3 + (dwp + 1);
                    int np = (sh + dh) * 512 + (sw + dwp);
                    float ssd1 = cn1[np] + cn2c - 2.f * a1[k];
                    float ssd2 = cn2[np] + cn1c - 2.f * a2[k];
                    float e1 = 1.0f / sqrtf(ssd1 + 0.01f);
                    float e2 = 1.0f / sqrtf(ssd2 + 0.01f);
                    a1[k] = e1;
                    a2[k] = e2;
                    s1 += e1;
                    s2 += e2;
                }
            float i1 = 1.0f / s1, i2 = 1.0f / s2;
#pragma unroll
            for (int k = 0; k < 9; ++k) {
                d[k] = a1[k] * i1;
                d[9 + k] = a2[k] * i2;
            }
        } else {
#pragma unroll
            for (int k = 0; k < 18; ++k) d[k] = 1.0f / 9.0f;
        }
#pragma unroll
        for (int k = 0; k < 18; ++k) {
            float v = fmaxf(d[k], __shfl_xor(d[k], 4, 64));
            d[k] = fmaxf(v, __shfl_xor(v, 32, 64));
        }
        d[18] = 2.0f * (sh | 1) / 511.0f - 1.0f;
        d[19] = 2.0f * (sw | 1) / 511.0f - 1.0f;
        if ((tid & 36) == 0) {
            int opix = (sh >> 1) * 256 + (sw >> 1);
#pragma unroll
            for (int j = 0; j < 5; ++j)
                feat[(quad * 5 + j) * 65536 + opix] = d[quad * 5 + j];
        }
    } else if (bid < 5120) {
        // ---------- pm256 -> feat ch20..39 (norm/dot SSD) ----------
        int i = bid - 4096;
        int bx = i & 31, by = i >> 5;
        int quad = tid & 3;
        int pl = tid >> 2;
        int px = pl & 7, py = pl >> 3;
        int w = bx * 8 + px;
        int h = by * 8 + py;
        bool interior = (h >= 1 && h <= 254 && w >= 1 && w <= 254);
        const float* b1 = p1 + (h * 256 + w) * 32 + quad * 8;
        const float* b2 = p2 + (h * 256 + w) * 32 + quad * 8;
        float a1[9], a2[9];
#pragma unroll
        for (int k = 0; k < 9; ++k) { a1[k] = 0.f; a2[k] = 0.f; }
        if (interior) {
            float4 y1a = ((const float4*)b1)[0], y1b = ((const float4*)b1)[1];
            float4 y2a = ((const float4*)b2)[0], y2b = ((const float4*)b2)[1];
#pragma unroll
            for (int dh = -1; dh <= 1; ++dh)
#pragma unroll
                for (int dwp = -1; dwp <= 1; ++dwp) {
                    int k = (dh + 1) * 3 + (dwp + 1);
                    const float4* n1 =
                        (const float4*)(b1 + (dh * 256 + dwp) * 32);
                    const float4* n2 =
                        (const float4*)(b2 + (dh * 256 + dwp) * 32);
                    float4 na = n1[0], nA = n1[1], nb = n2[0], nB = n2[1];
                    float d1 = 0.f, d2 = 0.f;
                    d1 = fmaf(na.x, y2a.x, d1);
                    d1 = fmaf(na.y, y2a.y, d1);
                    d1 = fmaf(na.z, y2a.z, d1);
                    d1 = fmaf(na.w, y2a.w, d1);
                    d1 = fmaf(nA.x, y2b.x, d1);
                    d1 = fmaf(nA.y, y2b.y, d1);
                    d1 = fmaf(nA.z, y2b.z, d1);
                    d1 = fmaf(nA.w, y2b.w, d1);
                    d2 = fmaf(nb.x, y1a.x, d2);
                    d2 = fmaf(nb.y, y1a.y, d2);
                    d2 = fmaf(nb.z, y1a.z, d2);
                    d2 = fmaf(nb.w, y1a.w, d2);
                    d2 = fmaf(nB.x, y1b.x, d2);
                    d2 = fmaf(nB.y, y1b.y, d2);
                    d2 = fmaf(nB.z, y1b.z, d2);
                    d2 = fmaf(nB.w, y1b.w, d2);
                    a1[k] = d1;
                    a2[k] = d2;
                }
        }
#pragma unroll
        for (int k = 0; k < 9; ++k) {
            a1[k] += __shfl_xor(a1[k], 1, 64);
            a1[k] += __shfl_xor(a1[k], 2, 64);
            a2[k] += __shfl_xor(a2[k], 1, 64);
            a2[k] += __shfl_xor(a2[k], 2, 64);
        }
        float d[20];
        if (interior) {
            float pn1c = pn1[h * 256 + w];
            float pn2c = pn2[h * 256 + w];
            float s1 = 0.f, s2 = 0.f;
#pragma unroll
            for (int dh = -1; dh <= 1; ++dh)
#pragma unroll
                for (int dwp = -1; dwp <= 1; ++dwp) {
                    int k = (dh + 1) * 3 + (dwp + 1);
                    int np = (h + dh) * 256 + (w + dwp);
                    float ssd1 = pn1[np] + pn2c - 2.f * a1[k];
                    float ssd2 = pn2[np] + pn1c - 2.f * a2[k];
                    float e1 = 1.0f / sqrtf(ssd1 + 0.01f);
                    float e2 = 1.0f / sqrtf(ssd2 + 0.01f);
                    a1[k] = e1;
                    a2[k] = e2;
                    s1 += e1;
                    s2 += e2;
                }
            float i1 = 1.0f / s1, i2 = 1.0f / s2;
#pragma unroll
            for (int k = 0; k < 9; ++k) {
                d[k] = a1[k] * i1;
                d[9 + k] = a2[k] * i2;
            }
        } else {
#pragma unroll
            for (int k = 0; k < 18; ++k) d[k] = 1.0f / 9.0f;
        }
        d[18] = 2.0f * h / 255.0f - 1.0f;
        d[19] = 2.0f * w / 255.0f - 1.0f;
        int pix = h * 256 + w;
#pragma unroll
        for (int j = 0; j < 5; ++j)
            feat[(20 + quad * 5 + j) * 65536 + pix] = d[quad * 5 + j];
    } else {
        // ---------------- dense_part -> part [R15 exact] ----------------
        float* sdiff = smem;            // [4][1296]
        float* swl = smem + 4 * 1296;   // [4][8][28]
        int i = bid - 5120;
        int bz = i >> 6;
        int rem = i & 63;
        int by = rem >> 3, bx = rem & 7;
        int tx = tid & 15, ty = tid >> 4;
        int h0 = by * 32, w0 = bx * 32;
        for (int idx = tid; idx < 1296; idx += 256) {
            int yy = idx / 36, xx = idx % 36;
            int gy = h0 + yy - 2, gx = w0 + xx - 2;
            float4 dv = make_float4(0.f, 0.f, 0.f, 0.f);
            if (gy >= 0 && gy < 256 && gx >= 0 && gx < 256) {
                const float4* q1 =
                    (const float4*)(p1 + (gy * 256 + gx) * 32 + bz * 4);
                const float4* q2 =
                    (const float4*)(p2 + (gy * 256 + gx) * 32 + bz * 4);
                float4 v1 = q1[0], v2 = q2[0];
                dv = make_float4(v1.x - v2.x, v1.y - v2.y, v1.z - v2.z,
                                 v1.w - v2.w);
            }
            sdiff[0 * 1296 + idx] = dv.x;
            sdiff[1 * 1296 + idx] = dv.y;
            sdiff[2 * 1296 + idx] = dv.z;
            sdiff[3 * 1296 + idx] = dv.w;
        }
        for (int idx = tid; idx < 4 * 8 * 28; idx += 256) {
            int ci = idx / 224, r = idx % 224;
            int o = r / 28, k = r % 28;
            swl[idx] = (k < 25) ? dw[o * 800 + (bz * 4 + ci) * 25 + k] : 0.f;
        }
        __syncthreads();
        float acc[4][8];
#pragma unroll
        for (int pq = 0; pq < 4; ++pq)
#pragma unroll
            for (int o = 0; o < 8; ++o) acc[pq][o] = 0.f;
        for (int ci = 0; ci < 4; ++ci) {
            float patch[6][6];
#pragma unroll
            for (int yy = 0; yy < 6; ++yy) {
                const float* rowp =
                    &sdiff[ci * 1296 + (2 * ty + yy) * 36 + 2 * tx];
#pragma unroll
                for (int cpair = 0; cpair < 3; ++cpair) {
                    float2 lp = *(const float2*)&rowp[2 * cpair];
                    patch[yy][2 * cpair] = lp.x;
                    patch[yy][2 * cpair + 1] = lp.y;
                }
            }
#pragma unroll
            for (int o = 0; o < 8; ++o) {
                float wreg[28];
                const float4* wp = (const float4*)&swl[(ci * 8 + o) * 28];
#pragma unroll
                for (int q = 0; q < 7; ++q) {
                    float4 wv = wp[q];
                    wreg[4 * q] = wv.x;
                    wreg[4 * q + 1] = wv.y;
                    wreg[4 * q + 2] = wv.z;
                    wreg[4 * q + 3] = wv.w;
                }
#pragma unroll
                for (int ky = 0; ky < 5; ++ky)
#pragma unroll
                    for (int kx = 0; kx < 5; ++kx) {
                        float wv = wreg[ky * 5 + kx];
#pragma unroll
                        for (int pq = 0; pq < 4; ++pq)
                            acc[pq][o] =
                                fmaf(wv, patch[ky + (pq >> 1)][kx + (pq & 1)],
                                     acc[pq][o]);
                    }
            }
        }
#pragma unroll
        for (int pq = 0; pq < 4; ++pq) {
            int h = h0 + 2 * ty + (pq >> 1), w = w0 + 2 * tx + (pq & 1);
            int pix = h * 256 + w;
#pragma unroll
            for (int o = 0; o < 8; ++o)
                part[bz * 524288 + o * 65536 + pix] = acc[pq][o];
        }
    }
}

// 1x1 conv 48->64 with dense_reduce folded in (ch40-47 from part). [R15]
__global__ __launch_bounds__(256) void f1_kernel(
    const float* __restrict__ feat, const float* __restrict__ part,
    const float* __restrict__ db, const float* __restrict__ f1w,
    const float* __restrict__ f1b, float* __restrict__ out) {
    __shared__ float sw[1536];
    __shared__ float sb[32];
    int og = blockIdx.y;
    int tid = threadIdx.x;
    for (int i = tid; i < 1536; i += 256) sw[i] = f1w[og * 1536 + i];
    if (tid < 32) sb[tid] = f1b[og * 32 + tid];
    __syncthreads();
    int pix = blockIdx.x * 256 + tid;
    float f[48];
#pragma unroll
    for (int c = 0; c < 40; ++c) f[c] = feat[c * 65536 + pix];
#pragma unroll
    for (int o = 0; o < 8; ++o) {
        float s = db[o];
#pragma unroll
        for (int z = 0; z < 8; ++z) s += part[z * 524288 + o * 65536 + pix];
        f[40 + o] = (s >= 0.f) ? s : 0.01f * s;
    }
#pragma unroll
    for (int o = 0; o < 32; ++o) {
        float a = sb[o];
        const float4* wv = (const float4*)&sw[o * 48];
#pragma unroll
        for (int c4 = 0; c4 < 12; ++c4) {
            float4 ww = wv[c4];
            a = fmaf(ww.x, f[c4 * 4], a);
            a = fmaf(ww.y, f[c4 * 4 + 1], a);
            a = fmaf(ww.z, f[c4 * 4 + 2], a);
            a = fmaf(ww.w, f[c4 * 4 + 3], a);
        }
        out[(og * 32 + o) * 65536 + pix] = a;
    }
}

// adaptive_max_pool3: one block per (channel, i, j). [R9 exact]
__global__ __launch_bounds__(256) void pool3_kernel(
    const float* __restrict__ f1out, float* __restrict__ pooled) {
    int b = blockIdx.x;  // 64*9
    int c = b / 9, ij = b % 9, i = ij / 3, j = ij % 3;
    int hs = (i * 256) / 3, he = ((i + 1) * 256 + 2) / 3;
    int ws = (j * 256) / 3, we = ((j + 1) * 256 + 2) / 3;
    const float* src = f1out + c * 65536;
    int nh = he - hs, nw = we - ws, tot = nh * nw;
    float m = -INFINITY;
    for (int t = threadIdx.x; t < tot; t += 256) {
        int r = t / nw, q = t - r * nw;
        m = fmaxf(m, src[(hs + r) * 256 + (ws + q)]);
    }
    for (int off = 32; off > 0; off >>= 1) m = fmaxf(m, __shfl_down(m, off, 64));
    __shared__ float red[4];
    if ((threadIdx.x & 63) == 0) red[threadIdx.x >> 6] = m;
    __syncthreads();
    if (threadIdx.x == 0)
        pooled[b] = fmaxf(fmaxf(red[0], red[1]), fmaxf(red[2], red[3]));
}

// f2 conv (64,3,3)->128, L2-normalize, f3 matmul -> 6, assemble 3x3 output.
__global__ __launch_bounds__(128) void final_kernel(
    const float* __restrict__ pooled, const float* __restrict__ f2w,
    const float* __restrict__ f2b, const float* __restrict__ f3w,
    const float* __restrict__ f3b, float* __restrict__ out) {
    __shared__ float xn[128];
    __shared__ float red[2];
    __shared__ float ov[6];
    int t = threadIdx.x;
    float a = f2b[t];
    for (int c = 0; c < 64; ++c)
#pragma unroll
        for (int k = 0; k < 9; ++k)
            a = fmaf(f2w[t * 576 + c * 9 + k], pooled[c * 9 + k], a);
    float sq = a * a;
    for (int off = 32; off > 0; off >>= 1) sq += __shfl_down(sq, off, 64);
    if ((t & 63) == 0) red[t >> 6] = sq;
    __syncthreads();
    float tmp = red[0] + red[1] + 0.001f;
    float scale = 1.0f / sqrtf(tmp);
    xn[t] = a * scale;
    __syncthreads();
    if (t < 6) {
        float o = f3b[t];
        for (int k = 0; k < 128; ++k) o = fmaf(f3w[t * 128 + k], xn[k], o);
        ov[t] = o;
    }
    __syncthreads();
    if (t < 9) {
        int r = t / 3, cc = t % 3;
        float v = 0.f;
        if (r < 2) {
            float x = ov[r * 3 + cc];
            float cl = fminf(fmaxf(x, -0.11f), 0.11f);
            v = cl + 0.01f * x;
        }
        if (r == cc) v += 1.0f;
        out[t] = v;
    }
}

extern "C" void kernel_launch(void* const* d_in, const int* in_sizes, int n_in,
                              void* d_out, int out_size, void* d_ws,
                              size_t ws_size, hipStream_t stream) {
    const float* x1 = (const float*)d_in[0];
    const float* x2 = (const float*)d_in[1];
    const float* enc_w = (const float*)d_in[2];
    const float* enc_b = (const float*)d_in[3];
    const float* embed_w = (const float*)d_in[4];
    const float* embed_b = (const float*)d_in[5];
    const float* dense_w = (const float*)d_in[6];
    const float* dense_b = (const float*)d_in[7];
    const float* f1_w = (const float*)d_in[8];
    const float* f1_b = (const float*)d_in[9];
    const float* f2_w = (const float*)d_in[10];
    const float* f2_b = (const float*)d_in[11];
    const float* f3_w = (const float*)d_in[12];
    const float* f3_b = (const float*)d_in[13];

    float* ws = (float*)d_ws;
    float* weff_t = ws;                 // 864
    float* beff = ws + 864;             // 32
    float* c1 = ws + 1024;              // 512*512*32 (ch-last)
    float* c2 = c1 + 8388608;
    float* p1 = c2 + 8388608;           // 256*256*32 (ch-last)
    float* p2 = p1 + 2097152;
    float* feat = p2 + 2097152;         // 48*256*256 planar; ch40-47 = cn
    float* pooled = feat + 3145728;     // 576 (pad 1024)
    float* pn1 = pooled + 1024;         // 65536
    float* pn2 = pn1 + 65536;           // 65536
    float* part = pn2 + 65536;          // 8*524288
    float* cn1 = feat + 40 * 65536;     // 262144 (feat ch40-43, unused by f1)
    float* cn2 = feat + 44 * 65536;     // 262144 (feat ch44-47)
    float* f1o = c1;                    // alias: c1 dead after mid

    fuse_weights_kernel<<<1, 256, 0, stream>>>(enc_w, enc_b, embed_w, embed_b,
                                               weff_t, beff);
    coding_kernel<<<dim3(32, 64, 2), dim3(16, 16), 0, stream>>>(
        x1, x2, weff_t, beff, c1, c2, p1, p2, cn1, cn2, pn1, pn2);
    mid_kernel<<<5632, 256, 0, stream>>>(c1, c2, p1, p2, cn1, cn2, pn1, pn2,
                                         dense_w, feat, part);
    f1_kernel<<<dim3(256, 2), 256, 0, stream>>>(feat, part, dense_b, f1_w,
                                                f1_b, f1o);
    pool3_kernel<<<576, 256, 0, stream>>>(f1o, pooled);
    final_kernel<<<1, 128, 0, stream>>>(pooled, f2_w, f2_b, f3_w, f3_b,
                                        (float*)d_out);
}

// Round 19
// 175.131 us; speedup vs baseline: 1.0351x; 1.0351x over previous
//
#include <hip/hip_runtime.h>
#include <math.h>

// ---------------------------------------------------------------------------
// MyNet: two 1024x1024x3 images -> 3x3 matrix.
// R19 = R15-exact restore (best measured: 175.2us). R16-R18 attacked mid
//      via LDS re-tile / LDS halving / norm-dot VALU halving; all regressed
//      or neutral -> mid is at a latency/issue equilibrium. Final config:
//      coding (R9 form, 67.6us) + fused mid (pm512+pm256+dense, 78.5us) +
//      f1(+dense_reduce fold) + pool3 + final; 6 dispatches.
// ---------------------------------------------------------------------------

__global__ void fuse_weights_kernel(const float* __restrict__ enc_w,
                                    const float* __restrict__ enc_b,
                                    const float* __restrict__ embed_w,
                                    const float* __restrict__ embed_b,
                                    float* __restrict__ weff_t,
                                    float* __restrict__ beff) {
    int t = threadIdx.x;
    for (int idx = t; idx < 27 * 32; idx += blockDim.x) {
        int r = idx >> 5, o = idx & 31;
        float s = 0.f;
        for (int k = 0; k < 24; ++k) s += embed_w[o * 24 + k] * enc_w[k * 27 + r];
        weff_t[idx] = s;
    }
    if (t < 32) {
        float s = embed_b[t];
        for (int k = 0; k < 24; ++k) s += embed_w[t * 24 + k] * enc_b[k];
        beff[t] = s;
    }
}

// Fused enc+embed 3x3 conv (3->32) + maxpool2 -> c (512^2, ch-last)
// + maxpool2 -> p (256^2, ch-last). Weights wave-uniform (SGPR). [R9 exact]
__global__ __launch_bounds__(256) void coding_kernel(
    const float* __restrict__ x1, const float* __restrict__ x2,
    const float* __restrict__ weff_t, const float* __restrict__ beff,
    float* __restrict__ c1, float* __restrict__ c2,
    float* __restrict__ p1, float* __restrict__ p2) {
    int tx = threadIdx.x, ty = threadIdx.y;
    int img = blockIdx.z;
    const float* x = img ? x2 : x1;
    float* c = img ? c2 : c1;
    float* p = img ? p2 : p1;
    int Y = blockIdx.y * 16 + ty;   // src row 0..1023
    int cx = blockIdx.x * 16 + tx;  // c col 0..511
    int X0 = 2 * cx;
    bool interior = (blockIdx.y > 0 && blockIdx.y < 63 &&
                     blockIdx.x > 0 && blockIdx.x < 31);
    float acc0[32], acc1[32];
#pragma unroll
    for (int o = 0; o < 32; ++o) {
        acc0[o] = beff[o];
        acc1[o] = acc0[o];
    }
#pragma unroll 1
    for (int ci = 0; ci < 3; ++ci) {
        float in[3][4];
        const float* xc = x + ci * 1048576;
        if (interior) {
#pragma unroll
            for (int r = 0; r < 3; ++r) {
                const float* row = xc + (Y - 1 + r) * 1024 + X0 - 1;
#pragma unroll
                for (int q = 0; q < 4; ++q) in[r][q] = row[q];
            }
        } else {
#pragma unroll
            for (int r = 0; r < 3; ++r)
#pragma unroll
                for (int q = 0; q < 4; ++q) {
                    int gy = Y - 1 + r, gx = X0 - 1 + q;
                    in[r][q] = (gy >= 0 && gy < 1024 && gx >= 0 && gx < 1024)
                                   ? xc[gy * 1024 + gx]
                                   : 0.f;
                }
        }
#pragma unroll
        for (int ky = 0; ky < 3; ++ky)
#pragma unroll
            for (int kx = 0; kx < 3; ++kx) {
                const float* wrow = weff_t + (ci * 9 + ky * 3 + kx) * 32;
                float xa = in[ky][kx];
                float xb = in[ky][kx + 1];
#pragma unroll
                for (int o = 0; o < 32; ++o) {
                    float wv = wrow[o];  // wave-uniform -> SGPR
                    acc0[o] = fmaf(wv, xa, acc0[o]);
                    acc1[o] = fmaf(wv, xb, acc1[o]);
                }
            }
    }
#pragma unroll
    for (int o = 0; o < 32; ++o) {
        float m = fmaxf(acc0[o], acc1[o]);
        acc0[o] = fmaxf(m, __shfl_xor(m, 16, 64));
    }
    int cpix = (Y >> 1) * 512 + cx;
    if ((ty & 1) == 0) {
        float4* cd = (float4*)(c + cpix * 32);
#pragma unroll
        for (int q = 0; q < 8; ++q)
            cd[q] = make_float4(acc0[4 * q], acc0[4 * q + 1], acc0[4 * q + 2],
                                acc0[4 * q + 3]);
    }
#pragma unroll
    for (int o = 0; o < 32; ++o) {
        float v = fmaxf(acc0[o], __shfl_xor(acc0[o], 1, 64));
        acc0[o] = fmaxf(v, __shfl_xor(v, 32, 64));
    }
    if (((ty & 3) == 0) && ((tx & 1) == 0)) {
        int ppix = (Y >> 2) * 256 + (cx >> 1);
        float4* pd = (float4*)(p + ppix * 32);
#pragma unroll
        for (int q = 0; q < 8; ++q)
            pd[q] = make_float4(acc0[4 * q], acc0[4 * q + 1], acc0[4 * q + 2],
                                acc0[4 * q + 3]);
    }
}

// Fused middle stage: blockIdx.x in [0,4096) = pm512 (8x8 px tile);
// [4096,5120) = pm256; [5120,5632) = dense_part. All R9-exact bodies.
__global__ __launch_bounds__(256) void mid_kernel(
    const float* __restrict__ c1, const float* __restrict__ c2,
    const float* __restrict__ p1, const float* __restrict__ p2,
    const float* __restrict__ dw, float* __restrict__ feat,
    float* __restrict__ part) {
    __shared__ float smem[4 * 1296 + 4 * 8 * 28];  // dense branch only
    int bid = blockIdx.x;
    int tid = threadIdx.x;
    if (bid < 4096) {
        // ---------------- pm512 + pool -> feat ch0..19 ----------------
        int bx = bid & 63, by = bid >> 6;
        int quad = tid & 3;
        int pl = tid >> 2;
        int px = pl & 7, py = pl >> 3;
        int sw = bx * 8 + px;
        int sh = by * 8 + py;
        bool interior = (sh >= 1 && sh <= 510 && sw >= 1 && sw <= 510);
        const float* b1 = c1 + (sh * 512 + sw) * 32 + quad * 8;
        const float* b2 = c2 + (sh * 512 + sw) * 32 + quad * 8;
        float a1[9], a2[9];
#pragma unroll
        for (int k = 0; k < 9; ++k) { a1[k] = 0.f; a2[k] = 0.f; }
        if (interior) {
            float4 y1a = ((const float4*)b1)[0], y1b = ((const float4*)b1)[1];
            float4 y2a = ((const float4*)b2)[0], y2b = ((const float4*)b2)[1];
#pragma unroll
            for (int dh = -1; dh <= 1; ++dh)
#pragma unroll
                for (int dwp = -1; dwp <= 1; ++dwp) {
                    int k = (dh + 1) * 3 + (dwp + 1);
                    const float4* n1 =
                        (const float4*)(b1 + (dh * 512 + dwp) * 32);
                    const float4* n2 =
                        (const float4*)(b2 + (dh * 512 + dwp) * 32);
                    float4 na = n1[0], nA = n1[1], nb = n2[0], nB = n2[1];
                    float s1 = a1[k], s2 = a2[k], t;
                    t = na.x - y2a.x; s1 = fmaf(t, t, s1);
                    t = na.y - y2a.y; s1 = fmaf(t, t, s1);
                    t = na.z - y2a.z; s1 = fmaf(t, t, s1);
                    t = na.w - y2a.w; s1 = fmaf(t, t, s1);
                    t = nA.x - y2b.x; s1 = fmaf(t, t, s1);
                    t = nA.y - y2b.y; s1 = fmaf(t, t, s1);
                    t = nA.z - y2b.z; s1 = fmaf(t, t, s1);
                    t = nA.w - y2b.w; s1 = fmaf(t, t, s1);
                    t = nb.x - y1a.x; s2 = fmaf(t, t, s2);
                    t = nb.y - y1a.y; s2 = fmaf(t, t, s2);
                    t = nb.z - y1a.z; s2 = fmaf(t, t, s2);
                    t = nb.w - y1a.w; s2 = fmaf(t, t, s2);
                    t = nB.x - y1b.x; s2 = fmaf(t, t, s2);
                    t = nB.y - y1b.y; s2 = fmaf(t, t, s2);
                    t = nB.z - y1b.z; s2 = fmaf(t, t, s2);
                    t = nB.w - y1b.w; s2 = fmaf(t, t, s2);
                    a1[k] = s1;
                    a2[k] = s2;
                }
        }
#pragma unroll
        for (int k = 0; k < 9; ++k) {
            a1[k] += __shfl_xor(a1[k], 1, 64);
            a1[k] += __shfl_xor(a1[k], 2, 64);
            a2[k] += __shfl_xor(a2[k], 1, 64);
            a2[k] += __shfl_xor(a2[k], 2, 64);
        }
        float d[20];
        if (interior) {
            float s1 = 0.f, s2 = 0.f;
#pragma unroll
            for (int k = 0; k < 9; ++k) {
                a1[k] = 1.0f / sqrtf(a1[k] + 0.01f);
                a2[k] = 1.0f / sqrtf(a2[k] + 0.01f);
                s1 += a1[k];
                s2 += a2[k];
            }
            float i1 = 1.0f / s1, i2 = 1.0f / s2;
#pragma unroll
            for (int k = 0; k < 9; ++k) {
                d[k] = a1[k] * i1;
                d[9 + k] = a2[k] * i2;
            }
        } else {
#pragma unroll
            for (int k = 0; k < 18; ++k) d[k] = 1.0f / 9.0f;
        }
#pragma unroll
        for (int k = 0; k < 18; ++k) {
            float v = fmaxf(d[k], __shfl_xor(d[k], 4, 64));
            d[k] = fmaxf(v, __shfl_xor(v, 32, 64));
        }
        d[18] = 2.0f * (sh | 1) / 511.0f - 1.0f;
        d[19] = 2.0f * (sw | 1) / 511.0f - 1.0f;
        if ((tid & 36) == 0) {
            int opix = (sh >> 1) * 256 + (sw >> 1);
#pragma unroll
            for (int j = 0; j < 5; ++j)
                feat[(quad * 5 + j) * 65536 + opix] = d[quad * 5 + j];
        }
    } else if (bid < 5120) {
        // ---------------- pm256 -> feat ch20..39 ----------------
        int i = bid - 4096;
        int bx = i & 31, by = i >> 5;
        int quad = tid & 3;
        int pl = tid >> 2;
        int px = pl & 7, py = pl >> 3;
        int w = bx * 8 + px;
        int h = by * 8 + py;
        bool interior = (h >= 1 && h <= 254 && w >= 1 && w <= 254);
        const float* b1 = p1 + (h * 256 + w) * 32 + quad * 8;
        const float* b2 = p2 + (h * 256 + w) * 32 + quad * 8;
        float a1[9], a2[9];
#pragma unroll
        for (int k = 0; k < 9; ++k) { a1[k] = 0.f; a2[k] = 0.f; }
        if (interior) {
            float4 y1a = ((const float4*)b1)[0], y1b = ((const float4*)b1)[1];
            float4 y2a = ((const float4*)b2)[0], y2b = ((const float4*)b2)[1];
#pragma unroll
            for (int dh = -1; dh <= 1; ++dh)
#pragma unroll
                for (int dwp = -1; dwp <= 1; ++dwp) {
                    int k = (dh + 1) * 3 + (dwp + 1);
                    const float4* n1 =
                        (const float4*)(b1 + (dh * 256 + dwp) * 32);
                    const float4* n2 =
                        (const float4*)(b2 + (dh * 256 + dwp) * 32);
                    float4 na = n1[0], nA = n1[1], nb = n2[0], nB = n2[1];
                    float s1 = a1[k], s2 = a2[k], t;
                    t = na.x - y2a.x; s1 = fmaf(t, t, s1);
                    t = na.y - y2a.y; s1 = fmaf(t, t, s1);
                    t = na.z - y2a.z; s1 = fmaf(t, t, s1);
                    t = na.w - y2a.w; s1 = fmaf(t, t, s1);
                    t = nA.x - y2b.x; s1 = fmaf(t, t, s1);
                    t = nA.y - y2b.y; s1 = fmaf(t, t, s1);
                    t = nA.z - y2b.z; s1 = fmaf(t, t, s1);
                    t = nA.w - y2b.w; s1 = fmaf(t, t, s1);
                    t = nb.x - y1a.x; s2 = fmaf(t, t, s2);
                    t = nb.y - y1a.y; s2 = fmaf(t, t, s2);
                    t = nb.z - y1a.z; s2 = fmaf(t, t, s2);
                    t = nb.w - y1a.w; s2 = fmaf(t, t, s2);
                    t = nB.x - y1b.x; s2 = fmaf(t, t, s2);
                    t = nB.y - y1b.y; s2 = fmaf(t, t, s2);
                    t = nB.z - y1b.z; s2 = fmaf(t, t, s2);
                    t = nB.w - y1b.w; s2 = fmaf(t, t, s2);
                    a1[k] = s1;
                    a2[k] = s2;
                }
        }
#pragma unroll
        for (int k = 0; k < 9; ++k) {
            a1[k] += __shfl_xor(a1[k], 1, 64);
            a1[k] += __shfl_xor(a1[k], 2, 64);
            a2[k] += __shfl_xor(a2[k], 1, 64);
            a2[k] += __shfl_xor(a2[k], 2, 64);
        }
        float d[20];
        if (interior) {
            float s1 = 0.f, s2 = 0.f;
#pragma unroll
            for (int k = 0; k < 9; ++k) {
                a1[k] = 1.0f / sqrtf(a1[k] + 0.01f);
                a2[k] = 1.0f / sqrtf(a2[k] + 0.01f);
                s1 += a1[k];
                s2 += a2[k];
            }
            float i1 = 1.0f / s1, i2 = 1.0f / s2;
#pragma unroll
            for (int k = 0; k < 9; ++k) {
                d[k] = a1[k] * i1;
                d[9 + k] = a2[k] * i2;
            }
        } else {
#pragma unroll
            for (int k = 0; k < 18; ++k) d[k] = 1.0f / 9.0f;
        }
        d[18] = 2.0f * h / 255.0f - 1.0f;
        d[19] = 2.0f * w / 255.0f - 1.0f;
        int pix = h * 256 + w;
#pragma unroll
        for (int j = 0; j < 5; ++j)
            feat[(20 + quad * 5 + j) * 65536 + pix] = d[quad * 5 + j];
    } else {
        // ---------------- dense_part -> part ----------------
        float* sdiff = smem;            // [4][1296]
        float* sw = smem + 4 * 1296;    // [4][8][28]
        int i = bid - 5120;
        int bz = i >> 6;
        int rem = i & 63;
        int by = rem >> 3, bx = rem & 7;
        int tx = tid & 15, ty = tid >> 4;
        int h0 = by * 32, w0 = bx * 32;
        for (int idx = tid; idx < 1296; idx += 256) {
            int yy = idx / 36, xx = idx % 36;
            int gy = h0 + yy - 2, gx = w0 + xx - 2;
            float4 dv = make_float4(0.f, 0.f, 0.f, 0.f);
            if (gy >= 0 && gy < 256 && gx >= 0 && gx < 256) {
                const float4* q1 =
                    (const float4*)(p1 + (gy * 256 + gx) * 32 + bz * 4);
                const float4* q2 =
                    (const float4*)(p2 + (gy * 256 + gx) * 32 + bz * 4);
                float4 v1 = q1[0], v2 = q2[0];
                dv = make_float4(v1.x - v2.x, v1.y - v2.y, v1.z - v2.z,
                                 v1.w - v2.w);
            }
            sdiff[0 * 1296 + idx] = dv.x;
            sdiff[1 * 1296 + idx] = dv.y;
            sdiff[2 * 1296 + idx] = dv.z;
            sdiff[3 * 1296 + idx] = dv.w;
        }
        for (int idx = tid; idx < 4 * 8 * 28; idx += 256) {
            int ci = idx / 224, r = idx % 224;
            int o = r / 28, k = r % 28;
            sw[idx] = (k < 25) ? dw[o * 800 + (bz * 4 + ci) * 25 + k] : 0.f;
        }
        __syncthreads();
        float acc[4][8];
#pragma unroll
        for (int pq = 0; pq < 4; ++pq)
#pragma unroll
            for (int o = 0; o < 8; ++o) acc[pq][o] = 0.f;
        for (int ci = 0; ci < 4; ++ci) {
            float patch[6][6];
#pragma unroll
            for (int yy = 0; yy < 6; ++yy) {
                const float* rowp =
                    &sdiff[ci * 1296 + (2 * ty + yy) * 36 + 2 * tx];
#pragma unroll
                for (int cpair = 0; cpair < 3; ++cpair) {
                    float2 lp = *(const float2*)&rowp[2 * cpair];
                    patch[yy][2 * cpair] = lp.x;
                    patch[yy][2 * cpair + 1] = lp.y;
                }
            }
#pragma unroll
            for (int o = 0; o < 8; ++o) {
                float wreg[28];
                const float4* wp = (const float4*)&sw[(ci * 8 + o) * 28];
#pragma unroll
                for (int q = 0; q < 7; ++q) {
                    float4 wv = wp[q];
                    wreg[4 * q] = wv.x;
                    wreg[4 * q + 1] = wv.y;
                    wreg[4 * q + 2] = wv.z;
                    wreg[4 * q + 3] = wv.w;
                }
#pragma unroll
                for (int ky = 0; ky < 5; ++ky)
#pragma unroll
                    for (int kx = 0; kx < 5; ++kx) {
                        float wv = wreg[ky * 5 + kx];
#pragma unroll
                        for (int pq = 0; pq < 4; ++pq)
                            acc[pq][o] =
                                fmaf(wv, patch[ky + (pq >> 1)][kx + (pq & 1)],
                                     acc[pq][o]);
                    }
            }
        }
#pragma unroll
        for (int pq = 0; pq < 4; ++pq) {
            int h = h0 + 2 * ty + (pq >> 1), w = w0 + 2 * tx + (pq & 1);
            int pix = h * 256 + w;
#pragma unroll
            for (int o = 0; o < 8; ++o)
                part[bz * 524288 + o * 65536 + pix] = acc[pq][o];
        }
    }
}

// 1x1 conv 48->64 (R9 form) with dense_reduce folded in: inputs ch0..39 from
// feat, ch40..47 computed inline from part (+bias+leaky).
__global__ __launch_bounds__(256) void f1_kernel(
    const float* __restrict__ feat, const float* __restrict__ part,
    const float* __restrict__ db, const float* __restrict__ f1w,
    const float* __restrict__ f1b, float* __restrict__ out) {
    __shared__ float sw[1536];
    __shared__ float sb[32];
    int og = blockIdx.y;
    int tid = threadIdx.x;
    for (int i = tid; i < 1536; i += 256) sw[i] = f1w[og * 1536 + i];
    if (tid < 32) sb[tid] = f1b[og * 32 + tid];
    __syncthreads();
    int pix = blockIdx.x * 256 + tid;
    float f[48];
#pragma unroll
    for (int c = 0; c < 40; ++c) f[c] = feat[c * 65536 + pix];
#pragma unroll
    for (int o = 0; o < 8; ++o) {
        float s = db[o];
#pragma unroll
        for (int z = 0; z < 8; ++z) s += part[z * 524288 + o * 65536 + pix];
        f[40 + o] = (s >= 0.f) ? s : 0.01f * s;
    }
#pragma unroll
    for (int o = 0; o < 32; ++o) {
        float a = sb[o];
        const float4* wv = (const float4*)&sw[o * 48];
#pragma unroll
        for (int c4 = 0; c4 < 12; ++c4) {
            float4 ww = wv[c4];
            a = fmaf(ww.x, f[c4 * 4], a);
            a = fmaf(ww.y, f[c4 * 4 + 1], a);
            a = fmaf(ww.z, f[c4 * 4 + 2], a);
            a = fmaf(ww.w, f[c4 * 4 + 3], a);
        }
        out[(og * 32 + o) * 65536 + pix] = a;
    }
}

// adaptive_max_pool3: one block per (channel, i, j). [R9 exact]
__global__ __launch_bounds__(256) void pool3_kernel(
    const float* __restrict__ f1out, float* __restrict__ pooled) {
    int b = blockIdx.x;  // 64*9
    int c = b / 9, ij = b % 9, i = ij / 3, j = ij % 3;
    int hs = (i * 256) / 3, he = ((i + 1) * 256 + 2) / 3;
    int ws = (j * 256) / 3, we = ((j + 1) * 256 + 2) / 3;
    const float* src = f1out + c * 65536;
    int nh = he - hs, nw = we - ws, tot = nh * nw;
    float m = -INFINITY;
    for (int t = threadIdx.x; t < tot; t += 256) {
        int r = t / nw, q = t - r * nw;
        m = fmaxf(m, src[(hs + r) * 256 + (ws + q)]);
    }
    for (int off = 32; off > 0; off >>= 1) m = fmaxf(m, __shfl_down(m, off, 64));
    __shared__ float red[4];
    if ((threadIdx.x & 63) == 0) red[threadIdx.x >> 6] = m;
    __syncthreads();
    if (threadIdx.x == 0)
        pooled[b] = fmaxf(fmaxf(red[0], red[1]), fmaxf(red[2], red[3]));
}

// f2 conv (64,3,3)->128, L2-normalize, f3 matmul -> 6, assemble 3x3 output.
__global__ __launch_bounds__(128) void final_kernel(
    const float* __restrict__ pooled, const float* __restrict__ f2w,
    const float* __restrict__ f2b, const float* __restrict__ f3w,
    const float* __restrict__ f3b, float* __restrict__ out) {
    __shared__ float xn[128];
    __shared__ float red[2];
    __shared__ float ov[6];
    int t = threadIdx.x;
    float a = f2b[t];
    for (int c = 0; c < 64; ++c)
#pragma unroll
        for (int k = 0; k < 9; ++k)
            a = fmaf(f2w[t * 576 + c * 9 + k], pooled[c * 9 + k], a);
    float sq = a * a;
    for (int off = 32; off > 0; off >>= 1) sq += __shfl_down(sq, off, 64);
    if ((t & 63) == 0) red[t >> 6] = sq;
    __syncthreads();
    float tmp = red[0] + red[1] + 0.001f;
    float scale = 1.0f / sqrtf(tmp);
    xn[t] = a * scale;
    __syncthreads();
    if (t < 6) {
        float o = f3b[t];
        for (int k = 0; k < 128; ++k) o = fmaf(f3w[t * 128 + k], xn[k], o);
        ov[t] = o;
    }
    __syncthreads();
    if (t < 9) {
        int r = t / 3, cc = t % 3;
        float v = 0.f;
        if (r < 2) {
            float x = ov[r * 3 + cc];
            float cl = fminf(fmaxf(x, -0.11f), 0.11f);
            v = cl + 0.01f * x;
        }
        if (r == cc) v += 1.0f;
        out[t] = v;
    }
}

extern "C" void kernel_launch(void* const* d_in, const int* in_sizes, int n_in,
                              void* d_out, int out_size, void* d_ws,
                              size_t ws_size, hipStream_t stream) {
    const float* x1 = (const float*)d_in[0];
    const float* x2 = (const float*)d_in[1];
    const float* enc_w = (const float*)d_in[2];
    const float* enc_b = (const float*)d_in[3];
    const float* embed_w = (const float*)d_in[4];
    const float* embed_b = (const float*)d_in[5];
    const float* dense_w = (const float*)d_in[6];
    const float* dense_b = (const float*)d_in[7];
    const float* f1_w = (const float*)d_in[8];
    const float* f1_b = (const float*)d_in[9];
    const float* f2_w = (const float*)d_in[10];
    const float* f2_b = (const float*)d_in[11];
    const float* f3_w = (const float*)d_in[12];
    const float* f3_b = (const float*)d_in[13];

    float* ws = (float*)d_ws;
    float* weff_t = ws;                 // 864
    float* beff = ws + 864;             // 32
    float* c1 = ws + 1024;              // 512*512*32 (ch-last)
    float* c2 = c1 + 8388608;
    float* p1 = c2 + 8388608;           // 256*256*32 (ch-last)
    float* p2 = p1 + 2097152;
    float* feat = p2 + 2097152;         // 48*256*256 (planar; ch40-47 unused)
    float* pooled = feat + 3145728;     // 576
    float* part = pooled + 1024;        // 8*524288 = 4194304
    float* f1o = c1;                    // alias: c1 dead after mid

    fuse_weights_kernel<<<1, 256, 0, stream>>>(enc_w, enc_b, embed_w, embed_b,
                                               weff_t, beff);
    coding_kernel<<<dim3(32, 64, 2), dim3(16, 16), 0, stream>>>(
        x1, x2, weff_t, beff, c1, c2, p1, p2);
    mid_kernel<<<5632, 256, 0, stream>>>(c1, c2, p1, p2, dense_w, feat, part);
    f1_kernel<<<dim3(256, 2), 256, 0, stream>>>(feat, part, dense_b, f1_w,
                                                f1_b, f1o);
    pool3_kernel<<<576, 256, 0, stream>>>(f1o, pooled);
    final_kernel<<<1, 128, 0, stream>>>(pooled, f2_w, f2_b, f3_w, f3_b,
                                        (float*)d_out);
}